// Round 2
// baseline (245.530 us; speedup 1.0000x reference)
//
#include <hip/hip_runtime.h>
#include <hip/hip_bf16.h>

typedef float f32x4 __attribute__((ext_vector_type(4)));
typedef __bf16 bf16x8 __attribute__((ext_vector_type(8)));
typedef unsigned short u16;

// ---------------- fp32 -> bf16 (RNE) ----------------
__device__ inline u16 f2bf(float f) {
    unsigned int u = __float_as_uint(f);
    unsigned int r = (u + 0x7fffu + ((u >> 16) & 1u)) >> 16;
    return (u16)r;
}

// Convert node embeddings fp32 -> bf16, 4 floats/thread.
__global__ __launch_bounds__(256) void cvt_emb_kernel(const float* __restrict__ in,
                                                      u16* __restrict__ out, int n4) {
    int i = blockIdx.x * blockDim.x + threadIdx.x;
    if (i >= n4) return;
    float4 v = ((const float4*)in)[i];
    unsigned int lo = (unsigned int)f2bf(v.x) | ((unsigned int)f2bf(v.y) << 16);
    unsigned int hi = (unsigned int)f2bf(v.z) | ((unsigned int)f2bf(v.w) << 16);
    uint2 o; o.x = lo; o.y = hi;
    ((uint2*)out)[i] = o;
}

// W1 [256][64] fp32 row-major -> W1^T bf16 [64][256].
// 64 blocks x 256 threads: one element per thread (round 1's single-block
// version was ~60 us of serial latency).
__global__ __launch_bounds__(256) void cvt_w1_kernel(const float* __restrict__ W1,
                                                     u16* __restrict__ w1t) {
    int i = blockIdx.x * blockDim.x + threadIdx.x;
    if (i >= 256 * 64) return;
    int n = i >> 8, k = i & 255;
    w1t[i] = f2bf(W1[k * 64 + n]);
}

// ---------------- main fused kernel ----------------
// One wave owns 16 edges per tile. NO LDS, NO barriers: A-fragments are
// gathered directly into VGPRs. For fixed kb, lanes (l15, quad=0..3) read
// 4 contiguous 16B chunks of edge l15's feature -> each 64B cache line is
// fully consumed by one instruction (same coalescing as the DMA version,
// minus the LDS round-trip and the vmcnt(0) barrier drain).
// Edge-index load is software-pipelined one tile ahead.
__global__ __launch_bounds__(256, 2) void edge_mlp_kernel(
    const u16* __restrict__ emb,   // [N][128] bf16
    const int* __restrict__ idx,   // [2][E]
    const u16* __restrict__ w1t,   // [64][256] bf16
    const float* __restrict__ b1,  // [64]
    const float* __restrict__ w2,  // [64]
    const float* __restrict__ b2,  // [1]
    float* __restrict__ out,       // [E]
    int E, int nTiles) {
    const int tid  = threadIdx.x;
    const int w    = tid >> 6;
    const int lane = tid & 63;
    const int quad = lane >> 4;
    const int l15  = lane & 15;

    // B fragments in registers for the whole kernel:
    // bfrag[kb][t]: lane holds B[k = kb*32 + quad*8 + j][n = t*16 + l15]
    bf16x8 bfrag[8][4];
#pragma unroll
    for (int t = 0; t < 4; ++t) {
        const u16* bp = w1t + (t * 16 + l15) * 256 + quad * 8;
#pragma unroll
        for (int kb = 0; kb < 8; ++kb)
            bfrag[kb][t] = *(const bf16x8*)(bp + kb * 32);
    }
    float b1v[4], w2v[4];
#pragma unroll
    for (int t = 0; t < 4; ++t) {
        b1v[t] = b1[t * 16 + l15];
        w2v[t] = w2[t * 16 + l15];
    }
    const float b2v = b2[0];

    const int gw     = blockIdx.x * 4 + w;  // global wave id
    const int stride = gridDim.x * 4;

    // idx layout: lanes 0..15 = src node of edge l15, lanes 16..31 = tgt.
    auto load_idx = [&](int tile) -> int {
        int v = 0;
        if (lane < 32) {
            int ge = tile * 16 + l15;
            if (ge >= E) ge = E - 1;
            v = idx[quad * E + ge];  // quad == half for lanes < 32
        }
        return v;
    };

    int idxv = load_idx(gw);

    for (int tile = gw; tile < nTiles; tile += stride) {
        // issue next tile's idx load early (pipelined one ahead)
        int nt   = tile + stride;
        int idxn = load_idx(nt < nTiles ? nt : tile);

        int srcn = __shfl(idxv, l15, 64);
        int tgtn = __shfl(idxv, 16 + l15, 64);
        const u16* ps = emb + (long)srcn * 128 + quad * 8;
        const u16* pt = emb + (long)tgtn * 128 + quad * 8;

        // A-frag gather: a[kb] = feature[edge l15][kb*32 + quad*8 .. +8]
        bf16x8 a[8];
#pragma unroll
        for (int kb = 0; kb < 4; ++kb) a[kb] = *(const bf16x8*)(ps + kb * 32);
#pragma unroll
        for (int kb = 0; kb < 4; ++kb) a[4 + kb] = *(const bf16x8*)(pt + kb * 32);

        f32x4 acc[4];
#pragma unroll
        for (int t = 0; t < 4; ++t)
#pragma unroll
            for (int r = 0; r < 4; ++r) acc[t][r] = 0.0f;

#pragma unroll
        for (int kb = 0; kb < 8; ++kb)
#pragma unroll
            for (int t = 0; t < 4; ++t)
                acc[t] = __builtin_amdgcn_mfma_f32_16x16x32_bf16(a[kb], bfrag[kb][t],
                                                                 acc[t], 0, 0, 0);

        // Epilogue: h = relu(acc + b1); score partial = sum_n h*w2 over this
        // lane's column; shfl-xor reduce over the 16 cols in each quad group.
        float p0 = 0.f, p1 = 0.f, p2 = 0.f, p3 = 0.f;
#pragma unroll
        for (int t = 0; t < 4; ++t) {
            float h;
            h = acc[t][0] + b1v[t]; p0 += (h > 0.f) ? h * w2v[t] : 0.f;
            h = acc[t][1] + b1v[t]; p1 += (h > 0.f) ? h * w2v[t] : 0.f;
            h = acc[t][2] + b1v[t]; p2 += (h > 0.f) ? h * w2v[t] : 0.f;
            h = acc[t][3] + b1v[t]; p3 += (h > 0.f) ? h * w2v[t] : 0.f;
        }
#pragma unroll
        for (int m = 1; m <= 8; m <<= 1) {
            p0 += __shfl_xor(p0, m, 64);
            p1 += __shfl_xor(p1, m, 64);
            p2 += __shfl_xor(p2, m, 64);
            p3 += __shfl_xor(p3, m, 64);
        }
        // C layout: col = l15, row = quad*4 + reg -> edge = tile*16 + quad*4 + r
        if (l15 < 4) {
            float v = ((l15 == 0) ? p0 : (l15 == 1) ? p1 : (l15 == 2) ? p2 : p3) + b2v;
            int eo = tile * 16 + quad * 4 + l15;
            if (eo < E) out[eo] = v;
        }
        idxv = idxn;
    }
}

extern "C" void kernel_launch(void* const* d_in, const int* in_sizes, int n_in,
                              void* d_out, int out_size, void* d_ws, size_t ws_size,
                              hipStream_t stream) {
    const float* emb_f = (const float*)d_in[0];
    const int*   idx   = (const int*)d_in[1];
    const float* W1    = (const float*)d_in[2];
    const float* b1    = (const float*)d_in[3];
    const float* W2    = (const float*)d_in[4];
    const float* b2    = (const float*)d_in[5];
    float* out = (float*)d_out;

    const int embN = in_sizes[0];       // N_NODES * 128
    const int E    = in_sizes[1] / 2;

    u16* emb_bf = (u16*)d_ws;
    u16* w1t    = emb_bf + embN;        // 32 KB right after embeddings

    int n4 = embN / 4;
    cvt_emb_kernel<<<(n4 + 255) / 256, 256, 0, stream>>>(emb_f, emb_bf, n4);
    cvt_w1_kernel<<<64, 256, 0, stream>>>(W1, w1t);

    int nTiles = (E + 15) / 16;
    edge_mlp_kernel<<<1024, 256, 0, stream>>>(emb_bf, idx, w1t, b1, W2, b2, out,
                                              E, nTiles);
}

// Round 3
// 220.329 us; speedup vs baseline: 1.1144x; 1.1144x over previous
//
#include <hip/hip_runtime.h>
#include <hip/hip_bf16.h>

typedef float f32x4 __attribute__((ext_vector_type(4)));
typedef __bf16 bf16x8 __attribute__((ext_vector_type(8)));
typedef unsigned short u16;

// ---------------- fp32 -> bf16 (RNE) ----------------
__device__ inline u16 f2bf(float f) {
    unsigned int u = __float_as_uint(f);
    unsigned int r = (u + 0x7fffu + ((u >> 16) & 1u)) >> 16;
    return (u16)r;
}

// Convert node embeddings fp32 -> bf16, 4 floats/thread.
__global__ __launch_bounds__(256) void cvt_emb_kernel(const float* __restrict__ in,
                                                      u16* __restrict__ out, int n4) {
    int i = blockIdx.x * blockDim.x + threadIdx.x;
    if (i >= n4) return;
    float4 v = ((const float4*)in)[i];
    unsigned int lo = (unsigned int)f2bf(v.x) | ((unsigned int)f2bf(v.y) << 16);
    unsigned int hi = (unsigned int)f2bf(v.z) | ((unsigned int)f2bf(v.w) << 16);
    uint2 o; o.x = lo; o.y = hi;
    ((uint2*)out)[i] = o;
}

// W1 [256][64] fp32 -> bf16 W1^T in MFMA *fragment order*:
// w1t[((kb*4+t)*64 + lane)*8 + j] = W1[k = kb*32 + (lane>>4)*8 + j][n = t*16 + (lane&15)]
// so the main kernel's B-frag read is ds_read_b128 at base + lane*16 (conflict-free).
__global__ __launch_bounds__(256) void cvt_w1_kernel(const float* __restrict__ W1,
                                                     u16* __restrict__ w1t) {
    int i = blockIdx.x * 256 + threadIdx.x;   // 0..16383
    if (i >= 256 * 64) return;
    int j    = i & 7;
    int fl   = i >> 3;       // 0..2047
    int lane = fl & 63;
    int kbt  = fl >> 6;      // 0..31 = kb*4 + t
    int kb   = kbt >> 2, t = kbt & 3;
    int k = kb * 32 + (lane >> 4) * 8 + j;
    int n = t * 16 + (lane & 15);
    w1t[i] = f2bf(W1[k * 64 + n]);
}

// ---------------- main fused kernel ----------------
// One wave owns 64 edges per tile (4 MFMA M-subtiles). W1^T lives in LDS in
// fragment order (staged once, one barrier, then barrier-free main loop).
// A-fragments gathered direct to VGPR: for fixed (m,kb), the 4 quads of a
// lane-group read one full 64B line of edge l15's feature row.
// Per tile: 128 MFMA (~5000 SIMD-cyc wall at 2 waves/SIMD) vs ~900 cyc gather
// latency head -> latency hidden without explicit pipelining; idx load is
// still pipelined one tile ahead.
__global__ __launch_bounds__(256, 2) void edge_mlp_kernel(
    const u16* __restrict__ emb,   // [N][128] bf16
    const int* __restrict__ idx,   // [2][E]
    const u16* __restrict__ w1t,   // fragment-ordered W1^T bf16 (32 KB)
    const float* __restrict__ b1,  // [64]
    const float* __restrict__ w2,  // [64]
    const float* __restrict__ b2,  // [1]
    float* __restrict__ out,       // [E]
    int E, int nTiles) {
    __shared__ __align__(16) u16 bsh[32 * 64 * 8];  // 32 KB, frag order

    const int tid  = threadIdx.x;
    const int w    = tid >> 6;
    const int lane = tid & 63;
    const int quad = lane >> 4;
    const int l15  = lane & 15;

    // Stage B fragments into LDS once (lane-contiguous b128 copy).
    {
        const uint4* src = (const uint4*)w1t;
        uint4* dst = (uint4*)bsh;
#pragma unroll
        for (int i = 0; i < 8; ++i) dst[tid + i * 256] = src[tid + i * 256];
    }
    float b1v[4], w2v[4];
#pragma unroll
    for (int t = 0; t < 4; ++t) {
        b1v[t] = b1[t * 16 + l15];
        w2v[t] = w2[t * 16 + l15];
    }
    const float b2v = b2[0];
    __syncthreads();  // only barrier in the kernel

    const int gw     = blockIdx.x * 4 + w;
    const int stride = gridDim.x * 4;

    // lane e holds src/tgt node index of edge tile*64+e
    auto ld_idx = [&](int tile, int& s, int& t_) {
        int e = tile * 64 + lane;
        if (e >= E) e = E - 1;
        s  = idx[e];
        t_ = idx[E + e];
    };

    int is = 0, it = 0;
    ld_idx(gw < nTiles ? gw : 0, is, it);

    for (int tile = gw; tile < nTiles; tile += stride) {
        // pipeline next tile's idx load
        int nt = tile + stride;
        int isn, itn;
        ld_idx(nt < nTiles ? nt : tile, isn, itn);

        // A gather: a[m][kb] = feature[edge m*16+l15][kb*32 + quad*8 .. +8]
        bf16x8 a[4][8];
#pragma unroll
        for (int m = 0; m < 4; ++m) {
            int srcn = __shfl(is, m * 16 + l15, 64);
            int tgtn = __shfl(it, m * 16 + l15, 64);
            const u16* ps = emb + (long)srcn * 128 + quad * 8;
            const u16* pt = emb + (long)tgtn * 128 + quad * 8;
#pragma unroll
            for (int kb = 0; kb < 4; ++kb) {
                a[m][kb]     = *(const bf16x8*)(ps + kb * 32);
                a[m][4 + kb] = *(const bf16x8*)(pt + kb * 32);
            }
        }

        f32x4 acc[4][4];
#pragma unroll
        for (int m = 0; m < 4; ++m)
#pragma unroll
            for (int t = 0; t < 4; ++t)
#pragma unroll
                for (int r = 0; r < 4; ++r) acc[m][t][r] = 0.0f;

#pragma unroll
        for (int kb = 0; kb < 8; ++kb) {
            bf16x8 bfr[4];
#pragma unroll
            for (int t = 0; t < 4; ++t)
                bfr[t] = *(const bf16x8*)(bsh + ((kb * 4 + t) * 64 + lane) * 8);
#pragma unroll
            for (int m = 0; m < 4; ++m)
#pragma unroll
                for (int t = 0; t < 4; ++t)
                    acc[m][t] = __builtin_amdgcn_mfma_f32_16x16x32_bf16(
                        a[m][kb], bfr[t], acc[m][t], 0, 0, 0);
        }

        // Epilogue: per subtile, h = relu(acc+b1), partial = sum h*w2 in-lane
        // over t, then shfl-xor over the 16 cols of the quad group.
#pragma unroll
        for (int m = 0; m < 4; ++m) {
            float p0 = 0.f, p1 = 0.f, p2 = 0.f, p3 = 0.f;
#pragma unroll
            for (int t = 0; t < 4; ++t) {
                float h;
                h = acc[m][t][0] + b1v[t]; p0 += fmaxf(h, 0.f) * w2v[t];
                h = acc[m][t][1] + b1v[t]; p1 += fmaxf(h, 0.f) * w2v[t];
                h = acc[m][t][2] + b1v[t]; p2 += fmaxf(h, 0.f) * w2v[t];
                h = acc[m][t][3] + b1v[t]; p3 += fmaxf(h, 0.f) * w2v[t];
            }
#pragma unroll
            for (int msk = 1; msk <= 8; msk <<= 1) {
                p0 += __shfl_xor(p0, msk, 64);
                p1 += __shfl_xor(p1, msk, 64);
                p2 += __shfl_xor(p2, msk, 64);
                p3 += __shfl_xor(p3, msk, 64);
            }
            // C layout: col = l15, row = quad*4 + r -> edge = tile*64 + m*16 + quad*4 + r
            if (l15 < 4) {
                float v = ((l15 == 0) ? p0 : (l15 == 1) ? p1 : (l15 == 2) ? p2 : p3) + b2v;
                int eo = tile * 64 + m * 16 + quad * 4 + l15;
                if (eo < E) out[eo] = v;
            }
        }
        is = isn; it = itn;
    }
}

extern "C" void kernel_launch(void* const* d_in, const int* in_sizes, int n_in,
                              void* d_out, int out_size, void* d_ws, size_t ws_size,
                              hipStream_t stream) {
    const float* emb_f = (const float*)d_in[0];
    const int*   idx   = (const int*)d_in[1];
    const float* W1    = (const float*)d_in[2];
    const float* b1    = (const float*)d_in[3];
    const float* W2    = (const float*)d_in[4];
    const float* b2    = (const float*)d_in[5];
    float* out = (float*)d_out;

    const int embN = in_sizes[0];       // N_NODES * 128
    const int E    = in_sizes[1] / 2;

    u16* emb_bf = (u16*)d_ws;
    u16* w1t    = emb_bf + embN;        // 32 KB right after embeddings

    int n4 = embN / 4;
    cvt_emb_kernel<<<(n4 + 255) / 256, 256, 0, stream>>>(emb_f, emb_bf, n4);
    cvt_w1_kernel<<<64, 256, 0, stream>>>(W1, w1t);

    int nTiles = (E + 63) / 64;
    edge_mlp_kernel<<<512, 256, 0, stream>>>(emb_bf, idx, w1t, b1, W2, b2, out,
                                             E, nTiles);
}

// Round 4
// 162.795 us; speedup vs baseline: 1.5082x; 1.3534x over previous
//
#include <hip/hip_runtime.h>
#include <hip/hip_bf16.h>

typedef float f32x4 __attribute__((ext_vector_type(4)));
typedef __bf16 bf16x8 __attribute__((ext_vector_type(8)));
typedef unsigned int u32x4 __attribute__((ext_vector_type(4)));
typedef unsigned short u16;

// fp32 -> bf16 RNE
__device__ inline u16 f2bf(float f) {
    unsigned int u = __float_as_uint(f);
    return (u16)((u + 0x7fffu + ((u >> 16) & 1u)) >> 16);
}

__device__ inline bf16x8 pack8(const float4 a, const float4 b) {
    union { u16 h[8]; bf16x8 v; } r;
    r.h[0] = f2bf(a.x); r.h[1] = f2bf(a.y); r.h[2] = f2bf(a.z); r.h[3] = f2bf(a.w);
    r.h[4] = f2bf(b.x); r.h[5] = f2bf(b.y); r.h[6] = f2bf(b.z); r.h[7] = f2bf(b.w);
    return r.v;
}

// B' = [W1_top | W1_bot] as 128(K) x 128(N), bf16, MFMA fragment order:
// wf[((kb*8+t)*64 + lane)*8 + j] = B'[kb*32 + (lane>>4)*8 + j][t*16 + (lane&15)]
// where B'[k][n] = W1[k + 128*(n>=64)][n&63].
__global__ __launch_bounds__(256) void cvt_w_kernel(const float* __restrict__ W1,
                                                    u16* __restrict__ wf) {
    int i = blockIdx.x * 256 + threadIdx.x;
    if (i >= 128 * 128) return;
    int j = i & 7, fl = i >> 3;
    int lane = fl & 63, kbt = fl >> 6;       // kbt in [0,32)
    int kb = kbt >> 3, t = kbt & 7;
    int k = kb * 32 + ((lane >> 4) & 3) * 8 + j;  // [0,128)
    int n = t * 16 + (lane & 15);                 // [0,128)
    int krow = k + ((n >= 64) ? 128 : 0);
    wf[i] = f2bf(W1[krow * 64 + (n & 63)]);
}

// Dense GEMM: uv[M][128] = emb[M][128] @ B'  (fp32 in, bf16 out, fp32 accum).
// Per wave: 32 rows x 128 cols; on-the-fly fp32->bf16 A conversion.
__global__ __launch_bounds__(256) void uv_gemm_kernel(
    const float* __restrict__ emb, const u16* __restrict__ wf,
    u16* __restrict__ uv, int M) {
    __shared__ __align__(16) u16 bsh[32 * 64 * 8];  // 32 KB, frag order

    const int tid = threadIdx.x;
    const int w = tid >> 6, lane = tid & 63, quad = lane >> 4, l15 = lane & 15;
    {
        const uint4* s = (const uint4*)wf;
        uint4* d = (uint4*)bsh;
#pragma unroll
        for (int i = 0; i < 8; ++i) d[tid + i * 256] = s[tid + i * 256];
    }
    __syncthreads();

    const int rb = blockIdx.x * 128 + w * 32;

    bf16x8 a[2][4];
#pragma unroll
    for (int m = 0; m < 2; ++m) {
        int row = rb + m * 16 + l15;
        if (row >= M) row = M - 1;
        const float* p = emb + (long)row * 128 + quad * 8;
#pragma unroll
        for (int kb = 0; kb < 4; ++kb) {
            float4 x = ((const float4*)(p + kb * 32))[0];
            float4 y = ((const float4*)(p + kb * 32))[1];
            a[m][kb] = pack8(x, y);
        }
    }

    f32x4 acc[2][8];
#pragma unroll
    for (int m = 0; m < 2; ++m)
#pragma unroll
        for (int t = 0; t < 8; ++t)
#pragma unroll
            for (int r = 0; r < 4; ++r) acc[m][t][r] = 0.0f;

#pragma unroll
    for (int kb = 0; kb < 4; ++kb)
#pragma unroll
        for (int t = 0; t < 8; ++t) {
            bf16x8 bf = *(const bf16x8*)(bsh + ((kb * 8 + t) * 64 + lane) * 8);
#pragma unroll
            for (int m = 0; m < 2; ++m)
                acc[m][t] = __builtin_amdgcn_mfma_f32_16x16x32_bf16(a[m][kb], bf,
                                                                    acc[m][t], 0, 0, 0);
        }

    // C layout: col = l15, row = quad*4 + r
#pragma unroll
    for (int m = 0; m < 2; ++m)
#pragma unroll
        for (int t = 0; t < 8; ++t)
#pragma unroll
            for (int r = 0; r < 4; ++r) {
                int row = rb + m * 16 + quad * 4 + r;
                if (row < M) uv[(long)row * 128 + t * 16 + l15] = f2bf(acc[m][t][r]);
            }
}

// Per-edge: score = relu(u[src] + v[tgt] + b1) . W2 + b2.
// 4 lanes per edge, each lane covers 16 of the 64 hidden dims (2x16B loads
// per table -> every wave-instruction consumes full 64B lines).
__global__ __launch_bounds__(256) void edge_score_kernel(
    const u16* __restrict__ uv, const int* __restrict__ idx,
    const float* __restrict__ b1, const float* __restrict__ w2,
    const float* __restrict__ b2, float* __restrict__ out, int E, int nT) {
    const int tid = threadIdx.x, w = tid >> 6, lane = tid & 63;
    const int e4 = lane >> 2, q = lane & 3;

    float b1v[16], w2v[16];
#pragma unroll
    for (int i = 0; i < 4; ++i) {
        float4 xb = ((const float4*)(b1 + q * 16))[i];
        float4 xw = ((const float4*)(w2 + q * 16))[i];
        b1v[i * 4 + 0] = xb.x; b1v[i * 4 + 1] = xb.y;
        b1v[i * 4 + 2] = xb.z; b1v[i * 4 + 3] = xb.w;
        w2v[i * 4 + 0] = xw.x; w2v[i * 4 + 1] = xw.y;
        w2v[i * 4 + 2] = xw.z; w2v[i * 4 + 3] = xw.w;
    }
    const float b2v = b2[0];

    const int gw = blockIdx.x * 4 + w, stride = gridDim.x * 4;

    auto ldidx = [&](int tile, int& s, int& t) {
        int e = tile * 16 + e4;
        if (e >= E) e = E - 1;
        s = idx[e];
        t = idx[E + e];
    };
    int src, tgt;
    ldidx(gw < nT ? gw : 0, src, tgt);

    for (int tile = gw; tile < nT; tile += stride) {
        int nt2 = tile + stride, sn, tn;
        ldidx(nt2 < nT ? nt2 : tile, sn, tn);

        const u16* up = uv + (long)src * 128 + q * 16;
        const u16* vp = uv + (long)tgt * 128 + 64 + q * 16;
        u32x4 U0 = *(const u32x4*)up;
        u32x4 U1 = *(const u32x4*)(up + 8);
        u32x4 V0 = *(const u32x4*)vp;
        u32x4 V1 = *(const u32x4*)(vp + 8);

        float s = 0.f;
#pragma unroll
        for (int i = 0; i < 4; ++i) {
            float ul = __uint_as_float(U0[i] << 16);
            float uh = __uint_as_float(U0[i] & 0xffff0000u);
            float vl = __uint_as_float(V0[i] << 16);
            float vh = __uint_as_float(V0[i] & 0xffff0000u);
            float h0 = ul + vl + b1v[2 * i];
            float h1 = uh + vh + b1v[2 * i + 1];
            s += fmaxf(h0, 0.f) * w2v[2 * i] + fmaxf(h1, 0.f) * w2v[2 * i + 1];
        }
#pragma unroll
        for (int i = 0; i < 4; ++i) {
            float ul = __uint_as_float(U1[i] << 16);
            float uh = __uint_as_float(U1[i] & 0xffff0000u);
            float vl = __uint_as_float(V1[i] << 16);
            float vh = __uint_as_float(V1[i] & 0xffff0000u);
            float h0 = ul + vl + b1v[8 + 2 * i];
            float h1 = uh + vh + b1v[8 + 2 * i + 1];
            s += fmaxf(h0, 0.f) * w2v[8 + 2 * i] + fmaxf(h1, 0.f) * w2v[8 + 2 * i + 1];
        }
        s += __shfl_xor(s, 1, 64);
        s += __shfl_xor(s, 2, 64);
        if (q == 0) {
            int e = tile * 16 + e4;
            if (e < E) out[e] = s + b2v;
        }
        src = sn; tgt = tn;
    }
}

extern "C" void kernel_launch(void* const* d_in, const int* in_sizes, int n_in,
                              void* d_out, int out_size, void* d_ws, size_t ws_size,
                              hipStream_t stream) {
    const float* emb_f = (const float*)d_in[0];
    const int*   idx   = (const int*)d_in[1];
    const float* W1    = (const float*)d_in[2];
    const float* b1    = (const float*)d_in[3];
    const float* W2    = (const float*)d_in[4];
    const float* b2    = (const float*)d_in[5];
    float* out = (float*)d_out;

    const int embN = in_sizes[0];      // N_NODES * 128
    const int M    = embN / 128;       // N_NODES
    const int E    = in_sizes[1] / 2;

    u16* uv = (u16*)d_ws;              // [M][128] bf16 = 25.6 MB
    u16* wf = uv + (long)M * 128;      // 32 KB fragment-ordered B'

    cvt_w_kernel<<<64, 256, 0, stream>>>(W1, wf);
    uv_gemm_kernel<<<(M + 127) / 128, 256, 0, stream>>>(emb_f, wf, uv, M);

    int nT = (E + 15) / 16;
    edge_score_kernel<<<1024, 256, 0, stream>>>(uv, idx, b1, W2, b2, out, E, nT);
}

// Round 5
// 160.716 us; speedup vs baseline: 1.5277x; 1.0129x over previous
//
#include <hip/hip_runtime.h>
#include <hip/hip_bf16.h>

typedef float f32x4 __attribute__((ext_vector_type(4)));
typedef __bf16 bf16x8 __attribute__((ext_vector_type(8)));
typedef _Float16 f16x2 __attribute__((ext_vector_type(2)));
typedef _Float16 f16x8 __attribute__((ext_vector_type(8)));
typedef unsigned short u16;

// fp32 -> bf16 RNE
__device__ inline u16 f2bf(float f) {
    unsigned int u = __float_as_uint(f);
    return (u16)((u + 0x7fffu + ((u >> 16) & 1u)) >> 16);
}

__device__ inline bf16x8 pack8(const float4 a, const float4 b) {
    union { u16 h[8]; bf16x8 v; } r;
    r.h[0] = f2bf(a.x); r.h[1] = f2bf(a.y); r.h[2] = f2bf(a.z); r.h[3] = f2bf(a.w);
    r.h[4] = f2bf(b.x); r.h[5] = f2bf(b.y); r.h[6] = f2bf(b.z); r.h[7] = f2bf(b.w);
    return r.v;
}

// B' = [W1_top | W1_bot] as 128(K) x 128(N), bf16, MFMA fragment order:
// wf[((kb*8+t)*64 + lane)*8 + j] = B'[kb*32 + (lane>>4)*8 + j][t*16 + (lane&15)]
// where B'[k][n] = W1[k + 128*(n>=64)][n&63].
__global__ __launch_bounds__(256) void cvt_w_kernel(const float* __restrict__ W1,
                                                    u16* __restrict__ wf) {
    int i = blockIdx.x * 256 + threadIdx.x;
    if (i >= 128 * 128) return;
    int j = i & 7, fl = i >> 3;
    int lane = fl & 63, kbt = fl >> 6;       // kbt in [0,32)
    int kb = kbt >> 3, t = kbt & 7;
    int k = kb * 32 + ((lane >> 4) & 3) * 8 + j;  // [0,128)
    int n = t * 16 + (lane & 15);                 // [0,128)
    int krow = k + ((n >= 64) ? 128 : 0);
    wf[i] = f2bf(W1[krow * 64 + (n & 63)]);
}

// Dense GEMM: uv[M][128] = emb[M][128] @ B'  (fp32 in, fp16 out, fp32 accum).
// Per wave: 32 rows x 128 cols; on-the-fly fp32->bf16 A conversion.
__global__ __launch_bounds__(256) void uv_gemm_kernel(
    const float* __restrict__ emb, const u16* __restrict__ wf,
    _Float16* __restrict__ uv, int M) {
    __shared__ __align__(16) u16 bsh[32 * 64 * 8];  // 32 KB, frag order

    const int tid = threadIdx.x;
    const int w = tid >> 6, lane = tid & 63, quad = lane >> 4, l15 = lane & 15;
    {
        const uint4* s = (const uint4*)wf;
        uint4* d = (uint4*)bsh;
#pragma unroll
        for (int i = 0; i < 8; ++i) d[tid + i * 256] = s[tid + i * 256];
    }
    __syncthreads();

    const int rb = blockIdx.x * 128 + w * 32;

    bf16x8 a[2][4];
#pragma unroll
    for (int m = 0; m < 2; ++m) {
        int row = rb + m * 16 + l15;
        if (row >= M) row = M - 1;
        const float* p = emb + (long)row * 128 + quad * 8;
#pragma unroll
        for (int kb = 0; kb < 4; ++kb) {
            float4 x = ((const float4*)(p + kb * 32))[0];
            float4 y = ((const float4*)(p + kb * 32))[1];
            a[m][kb] = pack8(x, y);
        }
    }

    f32x4 acc[2][8];
#pragma unroll
    for (int m = 0; m < 2; ++m)
#pragma unroll
        for (int t = 0; t < 8; ++t)
#pragma unroll
            for (int r = 0; r < 4; ++r) acc[m][t][r] = 0.0f;

#pragma unroll
    for (int kb = 0; kb < 4; ++kb)
#pragma unroll
        for (int t = 0; t < 8; ++t) {
            bf16x8 bf = *(const bf16x8*)(bsh + ((kb * 8 + t) * 64 + lane) * 8);
#pragma unroll
            for (int m = 0; m < 2; ++m)
                acc[m][t] = __builtin_amdgcn_mfma_f32_16x16x32_bf16(a[m][kb], bf,
                                                                    acc[m][t], 0, 0, 0);
        }

    // C layout: col = l15, row = quad*4 + r
#pragma unroll
    for (int m = 0; m < 2; ++m)
#pragma unroll
        for (int t = 0; t < 8; ++t)
#pragma unroll
            for (int r = 0; r < 4; ++r) {
                int row = rb + m * 16 + quad * 4 + r;
                if (row < M) uv[(long)row * 128 + t * 16 + l15] = (_Float16)acc[m][t][r];
            }
}

// Per-edge: score = relu(u[src] + v[tgt] + b1) . W2 + b2.
// 4 lanes per edge, each lane covers 16 of the 64 hidden dims.
// fp16 storage -> packed v_pk_add_f16 + v_dot2_f32_f16; VGPR <= 64 so
// __launch_bounds__(256,8) keeps 8 waves/SIMD to hide L3 gather latency.
__device__ inline f16x2 relu2(f16x2 x) {
    f16x2 r;
    r[0] = (x[0] > (_Float16)0.f) ? x[0] : (_Float16)0.f;
    r[1] = (x[1] > (_Float16)0.f) ? x[1] : (_Float16)0.f;
    return r;
}

__global__ __launch_bounds__(256, 8) void edge_score_kernel(
    const _Float16* __restrict__ uv, const int* __restrict__ idx,
    const float* __restrict__ b1, const float* __restrict__ w2,
    const float* __restrict__ b2, float* __restrict__ out, int E, int nT) {
    const int tid = threadIdx.x, w = tid >> 6, lane = tid & 63;
    const int e4 = lane >> 2, q = lane & 3;

    f16x2 b1h[8], w2h[8];
#pragma unroll
    for (int i = 0; i < 8; ++i) {
        b1h[i][0] = (_Float16)b1[q * 16 + 2 * i];
        b1h[i][1] = (_Float16)b1[q * 16 + 2 * i + 1];
        w2h[i][0] = (_Float16)w2[q * 16 + 2 * i];
        w2h[i][1] = (_Float16)w2[q * 16 + 2 * i + 1];
    }
    const float b2v = b2[0];

    const int gw = blockIdx.x * 4 + w, stride = gridDim.x * 4;

    auto ldidx = [&](int tile, int& s, int& t) {
        int e = tile * 16 + e4;
        if (e >= E) e = E - 1;
        s = idx[e];
        t = idx[E + e];
    };
    int src, tgt;
    ldidx(gw < nT ? gw : 0, src, tgt);

    union F8 { f16x8 v; f16x2 p[4]; };

    for (int tile = gw; tile < nT; tile += stride) {
        int nt2 = tile + stride, sn, tn;
        ldidx(nt2 < nT ? nt2 : tile, sn, tn);

        const _Float16* up = uv + (long)src * 128 + q * 16;
        const _Float16* vp = uv + (long)tgt * 128 + 64 + q * 16;
        F8 U0, U1, V0, V1;
        U0.v = *(const f16x8*)up;
        U1.v = *(const f16x8*)(up + 8);
        V0.v = *(const f16x8*)vp;
        V1.v = *(const f16x8*)(vp + 8);

        float s = 0.f;
#pragma unroll
        for (int i = 0; i < 4; ++i) {
            f16x2 h = relu2((U0.p[i] + V0.p[i]) + b1h[i]);
#if __has_builtin(__builtin_amdgcn_fdot2)
            s = __builtin_amdgcn_fdot2(h, w2h[i], s, false);
#else
            s += (float)h[0] * (float)w2h[i][0] + (float)h[1] * (float)w2h[i][1];
#endif
        }
#pragma unroll
        for (int i = 0; i < 4; ++i) {
            f16x2 h = relu2((U1.p[i] + V1.p[i]) + b1h[4 + i]);
#if __has_builtin(__builtin_amdgcn_fdot2)
            s = __builtin_amdgcn_fdot2(h, w2h[4 + i], s, false);
#else
            s += (float)h[0] * (float)w2h[4 + i][0] + (float)h[1] * (float)w2h[4 + i][1];
#endif
        }
        s += __shfl_xor(s, 1, 64);
        s += __shfl_xor(s, 2, 64);
        if (q == 0) {
            int e = tile * 16 + e4;
            if (e < E) out[e] = s + b2v;
        }
        src = sn; tgt = tn;
    }
}

extern "C" void kernel_launch(void* const* d_in, const int* in_sizes, int n_in,
                              void* d_out, int out_size, void* d_ws, size_t ws_size,
                              hipStream_t stream) {
    const float* emb_f = (const float*)d_in[0];
    const int*   idx   = (const int*)d_in[1];
    const float* W1    = (const float*)d_in[2];
    const float* b1    = (const float*)d_in[3];
    const float* W2    = (const float*)d_in[4];
    const float* b2    = (const float*)d_in[5];
    float* out = (float*)d_out;

    const int embN = in_sizes[0];      // N_NODES * 128
    const int M    = embN / 128;       // N_NODES
    const int E    = in_sizes[1] / 2;

    _Float16* uv = (_Float16*)d_ws;    // [M][128] fp16 = 25.6 MB
    u16* wf = (u16*)(uv + (long)M * 128);  // 32 KB fragment-ordered B'

    cvt_w_kernel<<<64, 256, 0, stream>>>(W1, wf);
    uv_gemm_kernel<<<(M + 127) / 128, 256, 0, stream>>>(emb_f, wf, uv, M);

    int nT = (E + 15) / 16;
    edge_score_kernel<<<2048, 256, 0, stream>>>(uv, idx, b1, W2, b2, out, E, nT);
}

// Round 6
// 159.793 us; speedup vs baseline: 1.5366x; 1.0058x over previous
//
#include <hip/hip_runtime.h>
#include <hip/hip_bf16.h>

typedef float f32x4 __attribute__((ext_vector_type(4)));
typedef __bf16 bf16x8 __attribute__((ext_vector_type(8)));
typedef _Float16 f16x2 __attribute__((ext_vector_type(2)));
typedef _Float16 f16x8 __attribute__((ext_vector_type(8)));
typedef unsigned short u16;

// fp32 -> bf16 RNE
__device__ inline u16 f2bf(float f) {
    unsigned int u = __float_as_uint(f);
    return (u16)((u + 0x7fffu + ((u >> 16) & 1u)) >> 16);
}

__device__ inline bf16x8 pack8(const float4 a, const float4 b) {
    union { u16 h[8]; bf16x8 v; } r;
    r.h[0] = f2bf(a.x); r.h[1] = f2bf(a.y); r.h[2] = f2bf(a.z); r.h[3] = f2bf(a.w);
    r.h[4] = f2bf(b.x); r.h[5] = f2bf(b.y); r.h[6] = f2bf(b.z); r.h[7] = f2bf(b.w);
    return r.v;
}

// B' = [W1_top | W1_bot] as 128(K) x 128(N), bf16, MFMA fragment order.
__global__ __launch_bounds__(256) void cvt_w_kernel(const float* __restrict__ W1,
                                                    u16* __restrict__ wf) {
    int i = blockIdx.x * 256 + threadIdx.x;
    if (i >= 128 * 128) return;
    int j = i & 7, fl = i >> 3;
    int lane = fl & 63, kbt = fl >> 6;
    int kb = kbt >> 3, t = kbt & 7;
    int k = kb * 32 + ((lane >> 4) & 3) * 8 + j;
    int n = t * 16 + (lane & 15);
    int krow = k + ((n >= 64) ? 128 : 0);
    wf[i] = f2bf(W1[krow * 64 + (n & 63)]);
}

// Dense GEMM: uv[M][128] = emb[M][128] @ B'  (fp32 in, fp16 out, fp32 accum).
__global__ __launch_bounds__(256) void uv_gemm_kernel(
    const float* __restrict__ emb, const u16* __restrict__ wf,
    _Float16* __restrict__ uv, int M) {
    __shared__ __align__(16) u16 bsh[32 * 64 * 8];  // 32 KB, frag order

    const int tid = threadIdx.x;
    const int w = tid >> 6, lane = tid & 63, quad = lane >> 4, l15 = lane & 15;
    {
        const uint4* s = (const uint4*)wf;
        uint4* d = (uint4*)bsh;
#pragma unroll
        for (int i = 0; i < 8; ++i) d[tid + i * 256] = s[tid + i * 256];
    }
    __syncthreads();

    const int rb = blockIdx.x * 128 + w * 32;

    bf16x8 a[2][4];
#pragma unroll
    for (int m = 0; m < 2; ++m) {
        int row = rb + m * 16 + l15;
        if (row >= M) row = M - 1;
        const float* p = emb + (long)row * 128 + quad * 8;
#pragma unroll
        for (int kb = 0; kb < 4; ++kb) {
            float4 x = ((const float4*)(p + kb * 32))[0];
            float4 y = ((const float4*)(p + kb * 32))[1];
            a[m][kb] = pack8(x, y);
        }
    }

    f32x4 acc[2][8];
#pragma unroll
    for (int m = 0; m < 2; ++m)
#pragma unroll
        for (int t = 0; t < 8; ++t)
#pragma unroll
            for (int r = 0; r < 4; ++r) acc[m][t][r] = 0.0f;

#pragma unroll
    for (int kb = 0; kb < 4; ++kb)
#pragma unroll
        for (int t = 0; t < 8; ++t) {
            bf16x8 bf = *(const bf16x8*)(bsh + ((kb * 8 + t) * 64 + lane) * 8);
#pragma unroll
            for (int m = 0; m < 2; ++m)
                acc[m][t] = __builtin_amdgcn_mfma_f32_16x16x32_bf16(a[m][kb], bf,
                                                                    acc[m][t], 0, 0, 0);
        }

#pragma unroll
    for (int m = 0; m < 2; ++m)
#pragma unroll
        for (int t = 0; t < 8; ++t)
#pragma unroll
            for (int r = 0; r < 4; ++r) {
                int row = rb + m * 16 + quad * 4 + r;
                if (row < M) uv[(long)row * 128 + t * 16 + l15] = (_Float16)acc[m][t][r];
            }
}

// Per-edge: score = relu(u[src] + v[tgt] + b1) . W2 + b2.
// 4 lanes per edge. NEW layout: each gather instruction reads one contiguous
// 64B line per edge (lane q -> row + q*16B), so U0/U1/V0/V1 touch exactly
// lines 0/1/2/3 of the two rows: 4 line-transactions per edge = the floor
// (was 8: lane stride 32B split every instruction across 2 lines).
// Lane q covers hidden dims {q*8..q*8+7} u {32+q*8..32+q*8+7}.
__device__ inline f16x2 relu2(f16x2 x) {
    f16x2 r;
    r[0] = (x[0] > (_Float16)0.f) ? x[0] : (_Float16)0.f;
    r[1] = (x[1] > (_Float16)0.f) ? x[1] : (_Float16)0.f;
    return r;
}

__global__ __launch_bounds__(256, 8) void edge_score_kernel(
    const _Float16* __restrict__ uv, const int* __restrict__ idx,
    const float* __restrict__ b1, const float* __restrict__ w2,
    const float* __restrict__ b2, float* __restrict__ out, int E, int nT) {
    const int tid = threadIdx.x, w = tid >> 6, lane = tid & 63;
    const int e4 = lane >> 2, q = lane & 3;

    // lane-local b1/w2: dims q*8+0..7 (i=0..3) and 32+q*8+0..7 (i=4..7)
    f16x2 b1h[8], w2h[8];
#pragma unroll
    for (int i = 0; i < 4; ++i) {
        b1h[i][0]     = (_Float16)b1[q * 8 + 2 * i];
        b1h[i][1]     = (_Float16)b1[q * 8 + 2 * i + 1];
        b1h[4 + i][0] = (_Float16)b1[32 + q * 8 + 2 * i];
        b1h[4 + i][1] = (_Float16)b1[32 + q * 8 + 2 * i + 1];
        w2h[i][0]     = (_Float16)w2[q * 8 + 2 * i];
        w2h[i][1]     = (_Float16)w2[q * 8 + 2 * i + 1];
        w2h[4 + i][0] = (_Float16)w2[32 + q * 8 + 2 * i];
        w2h[4 + i][1] = (_Float16)w2[32 + q * 8 + 2 * i + 1];
    }
    const float b2v = b2[0];

    const int gw = blockIdx.x * 4 + w, stride = gridDim.x * 4;

    auto ldidx = [&](int tile, int& s, int& t) {
        int e = tile * 16 + e4;
        if (e >= E) e = E - 1;
        s = idx[e];
        t = idx[E + e];
    };
    int src, tgt;
    ldidx(gw < nT ? gw : 0, src, tgt);

    union F8 { f16x8 v; f16x2 p[4]; };

    for (int tile = gw; tile < nT; tile += stride) {
        int nt2 = tile + stride, sn, tn;
        ldidx(nt2 < nT ? nt2 : tile, sn, tn);

        const _Float16* up = uv + (long)src * 128;
        const _Float16* vp = uv + (long)tgt * 128;
        F8 U0, U1, V0, V1;
        U0.v = *(const f16x8*)(up + q * 8);           // u dims q*8..+7   (line 0)
        U1.v = *(const f16x8*)(up + 32 + q * 8);      // u dims 32+q*8..  (line 1)
        V0.v = *(const f16x8*)(vp + 64 + q * 8);      // v dims q*8..+7   (line 2)
        V1.v = *(const f16x8*)(vp + 96 + q * 8);      // v dims 32+q*8..  (line 3)

        float s = 0.f;
#pragma unroll
        for (int i = 0; i < 4; ++i) {
            f16x2 h = relu2((U0.p[i] + V0.p[i]) + b1h[i]);
#if __has_builtin(__builtin_amdgcn_fdot2)
            s = __builtin_amdgcn_fdot2(h, w2h[i], s, false);
#else
            s += (float)h[0] * (float)w2h[i][0] + (float)h[1] * (float)w2h[i][1];
#endif
        }
#pragma unroll
        for (int i = 0; i < 4; ++i) {
            f16x2 h = relu2((U1.p[i] + V1.p[i]) + b1h[4 + i]);
#if __has_builtin(__builtin_amdgcn_fdot2)
            s = __builtin_amdgcn_fdot2(h, w2h[4 + i], s, false);
#else
            s += (float)h[0] * (float)w2h[4 + i][0] + (float)h[1] * (float)w2h[4 + i][1];
#endif
        }
        s += __shfl_xor(s, 1, 64);
        s += __shfl_xor(s, 2, 64);
        if (q == 0) {
            int e = tile * 16 + e4;
            if (e < E) out[e] = s + b2v;
        }
        src = sn; tgt = tn;
    }
}

extern "C" void kernel_launch(void* const* d_in, const int* in_sizes, int n_in,
                              void* d_out, int out_size, void* d_ws, size_t ws_size,
                              hipStream_t stream) {
    const float* emb_f = (const float*)d_in[0];
    const int*   idx   = (const int*)d_in[1];
    const float* W1    = (const float*)d_in[2];
    const float* b1    = (const float*)d_in[3];
    const float* W2    = (const float*)d_in[4];
    const float* b2    = (const float*)d_in[5];
    float* out = (float*)d_out;

    const int embN = in_sizes[0];      // N_NODES * 128
    const int M    = embN / 128;       // N_NODES
    const int E    = in_sizes[1] / 2;

    _Float16* uv = (_Float16*)d_ws;    // [M][128] fp16 = 25.6 MB
    u16* wf = (u16*)(uv + (long)M * 128);  // 32 KB fragment-ordered B'

    cvt_w_kernel<<<64, 256, 0, stream>>>(W1, wf);
    uv_gemm_kernel<<<(M + 127) / 128, 256, 0, stream>>>(emb_f, wf, uv, M);

    int nT = (E + 15) / 16;
    edge_score_kernel<<<2048, 256, 0, stream>>>(uv, idx, b1, W2, b2, out, E, nT);
}

// Round 7
// 159.752 us; speedup vs baseline: 1.5370x; 1.0003x over previous
//
#include <hip/hip_runtime.h>
#include <hip/hip_bf16.h>

typedef float f32x4 __attribute__((ext_vector_type(4)));
typedef __bf16 bf16x8 __attribute__((ext_vector_type(8)));
typedef _Float16 f16x2 __attribute__((ext_vector_type(2)));
typedef _Float16 f16x8 __attribute__((ext_vector_type(8)));
typedef unsigned short u16;

// fp32 -> bf16 RNE
__device__ inline u16 f2bf(float f) {
    unsigned int u = __float_as_uint(f);
    return (u16)((u + 0x7fffu + ((u >> 16) & 1u)) >> 16);
}

__device__ inline bf16x8 pack8(const float4 a, const float4 b) {
    union { u16 h[8]; bf16x8 v; } r;
    r.h[0] = f2bf(a.x); r.h[1] = f2bf(a.y); r.h[2] = f2bf(a.z); r.h[3] = f2bf(a.w);
    r.h[4] = f2bf(b.x); r.h[5] = f2bf(b.y); r.h[6] = f2bf(b.z); r.h[7] = f2bf(b.w);
    return r.v;
}

// B' = [W1_top | W1_bot] as 128(K) x 128(N), bf16, MFMA fragment order.
__global__ __launch_bounds__(256) void cvt_w_kernel(const float* __restrict__ W1,
                                                    u16* __restrict__ wf) {
    int i = blockIdx.x * 256 + threadIdx.x;
    if (i >= 128 * 128) return;
    int j = i & 7, fl = i >> 3;
    int lane = fl & 63, kbt = fl >> 6;
    int kb = kbt >> 3, t = kbt & 7;
    int k = kb * 32 + ((lane >> 4) & 3) * 8 + j;
    int n = t * 16 + (lane & 15);
    int krow = k + ((n >= 64) ? 128 : 0);
    wf[i] = f2bf(W1[krow * 64 + (n & 63)]);
}

// Dense GEMM: uv[M][128] = emb[M][128] @ B'  (fp32 in, fp16 out, fp32 accum).
__global__ __launch_bounds__(256) void uv_gemm_kernel(
    const float* __restrict__ emb, const u16* __restrict__ wf,
    _Float16* __restrict__ uv, int M) {
    __shared__ __align__(16) u16 bsh[32 * 64 * 8];  // 32 KB, frag order

    const int tid = threadIdx.x;
    const int w = tid >> 6, lane = tid & 63, quad = lane >> 4, l15 = lane & 15;
    {
        const uint4* s = (const uint4*)wf;
        uint4* d = (uint4*)bsh;
#pragma unroll
        for (int i = 0; i < 8; ++i) d[tid + i * 256] = s[tid + i * 256];
    }
    __syncthreads();

    const int rb = blockIdx.x * 128 + w * 32;

    bf16x8 a[2][4];
#pragma unroll
    for (int m = 0; m < 2; ++m) {
        int row = rb + m * 16 + l15;
        if (row >= M) row = M - 1;
        const float* p = emb + (long)row * 128 + quad * 8;
#pragma unroll
        for (int kb = 0; kb < 4; ++kb) {
            float4 x = ((const float4*)(p + kb * 32))[0];
            float4 y = ((const float4*)(p + kb * 32))[1];
            a[m][kb] = pack8(x, y);
        }
    }

    f32x4 acc[2][8];
#pragma unroll
    for (int m = 0; m < 2; ++m)
#pragma unroll
        for (int t = 0; t < 8; ++t)
#pragma unroll
            for (int r = 0; r < 4; ++r) acc[m][t][r] = 0.0f;

#pragma unroll
    for (int kb = 0; kb < 4; ++kb)
#pragma unroll
        for (int t = 0; t < 8; ++t) {
            bf16x8 bf = *(const bf16x8*)(bsh + ((kb * 8 + t) * 64 + lane) * 8);
#pragma unroll
            for (int m = 0; m < 2; ++m)
                acc[m][t] = __builtin_amdgcn_mfma_f32_16x16x32_bf16(a[m][kb], bf,
                                                                    acc[m][t], 0, 0, 0);
        }

#pragma unroll
    for (int m = 0; m < 2; ++m)
#pragma unroll
        for (int t = 0; t < 8; ++t)
#pragma unroll
            for (int r = 0; r < 4; ++r) {
                int row = rb + m * 16 + quad * 4 + r;
                if (row < M) uv[(long)row * 128 + t * 16 + l15] = (_Float16)acc[m][t][r];
            }
}

// Per-edge: score = relu(u[src] + v[tgt] + b1) . W2 + b2.
// 4 lanes per edge; each gather instruction reads one contiguous 64B line per
// edge. Round-7 changes: (a) x2 tile unroll -> 8 gather loads in flight per
// wave (tests miss-queue vs fill-port hypothesis); (b) non-temporal idx/out
// so streaming traffic doesn't evict uv lines from L2.
__device__ inline f16x2 relu2(f16x2 x) {
    f16x2 r;
    r[0] = (x[0] > (_Float16)0.f) ? x[0] : (_Float16)0.f;
    r[1] = (x[1] > (_Float16)0.f) ? x[1] : (_Float16)0.f;
    return r;
}

__global__ __launch_bounds__(256, 8) void edge_score_kernel(
    const _Float16* __restrict__ uv, const int* __restrict__ idx,
    const float* __restrict__ b1, const float* __restrict__ w2,
    const float* __restrict__ b2, float* __restrict__ out, int E, int nT) {
    const int tid = threadIdx.x, w = tid >> 6, lane = tid & 63;
    const int e4 = lane >> 2, q = lane & 3;

    // lane-local b1/w2: dims q*8+0..7 (i=0..3) and 32+q*8+0..7 (i=4..7)
    f16x2 b1h[8], w2h[8];
#pragma unroll
    for (int i = 0; i < 4; ++i) {
        b1h[i][0]     = (_Float16)b1[q * 8 + 2 * i];
        b1h[i][1]     = (_Float16)b1[q * 8 + 2 * i + 1];
        b1h[4 + i][0] = (_Float16)b1[32 + q * 8 + 2 * i];
        b1h[4 + i][1] = (_Float16)b1[32 + q * 8 + 2 * i + 1];
        w2h[i][0]     = (_Float16)w2[q * 8 + 2 * i];
        w2h[i][1]     = (_Float16)w2[q * 8 + 2 * i + 1];
        w2h[4 + i][0] = (_Float16)w2[32 + q * 8 + 2 * i];
        w2h[4 + i][1] = (_Float16)w2[32 + q * 8 + 2 * i + 1];
    }
    const float b2v = b2[0];

    const int gw = blockIdx.x * 4 + w, stride = gridDim.x * 4;
    const int step = stride * 2;

    auto ldidx = [&](int tile, int& s, int& t) {
        int e = tile * 16 + e4;
        if (e >= E) e = E - 1;
        s = __builtin_nontemporal_load(idx + e);
        t = __builtin_nontemporal_load(idx + E + e);
    };

    union F8 { f16x8 v; f16x2 p[4]; };

    auto score16 = [&](int src, int tgt) -> float {
        const _Float16* up = uv + (long)src * 128;
        const _Float16* vp = uv + (long)tgt * 128;
        F8 U0, U1, V0, V1;
        U0.v = *(const f16x8*)(up + q * 8);
        U1.v = *(const f16x8*)(up + 32 + q * 8);
        V0.v = *(const f16x8*)(vp + 64 + q * 8);
        V1.v = *(const f16x8*)(vp + 96 + q * 8);
        float s = 0.f;
#pragma unroll
        for (int i = 0; i < 4; ++i) {
            f16x2 h = relu2((U0.p[i] + V0.p[i]) + b1h[i]);
#if __has_builtin(__builtin_amdgcn_fdot2)
            s = __builtin_amdgcn_fdot2(h, w2h[i], s, false);
#else
            s += (float)h[0] * (float)w2h[i][0] + (float)h[1] * (float)w2h[i][1];
#endif
        }
#pragma unroll
        for (int i = 0; i < 4; ++i) {
            f16x2 h = relu2((U1.p[i] + V1.p[i]) + b1h[4 + i]);
#if __has_builtin(__builtin_amdgcn_fdot2)
            s = __builtin_amdgcn_fdot2(h, w2h[4 + i], s, false);
#else
            s += (float)h[0] * (float)w2h[4 + i][0] + (float)h[1] * (float)w2h[4 + i][1];
#endif
        }
        return s;
    };

    int sA, tA, sB, tB;
    {
        int t0 = (gw < nT) ? gw : 0;
        int t1 = (gw + stride < nT) ? (gw + stride) : t0;
        ldidx(t0, sA, tA);
        ldidx(t1, sB, tB);
    }

    for (int tile = gw; tile < nT; tile += step) {
        const int tileB = tile + stride;

        // prefetch next pair's indices
        int n0 = tile + step, n1 = tile + step + stride;
        int sA2, tA2, sB2, tB2;
        ldidx(n0 < nT ? n0 : tile, sA2, tA2);
        ldidx(n1 < nT ? n1 : tile, sB2, tB2);

        float sa = score16(sA, tA);
        float sb = score16(sB, tB);

        sa += __shfl_xor(sa, 1, 64);
        sa += __shfl_xor(sa, 2, 64);
        sb += __shfl_xor(sb, 1, 64);
        sb += __shfl_xor(sb, 2, 64);

        if (q == 0) {
            int ea = tile * 16 + e4;
            if (ea < E) __builtin_nontemporal_store(sa + b2v, out + ea);
            if (tileB < nT) {
                int eb = tileB * 16 + e4;
                if (eb < E) __builtin_nontemporal_store(sb + b2v, out + eb);
            }
        }
        sA = sA2; tA = tA2; sB = sB2; tB = tB2;
    }
}

extern "C" void kernel_launch(void* const* d_in, const int* in_sizes, int n_in,
                              void* d_out, int out_size, void* d_ws, size_t ws_size,
                              hipStream_t stream) {
    const float* emb_f = (const float*)d_in[0];
    const int*   idx   = (const int*)d_in[1];
    const float* W1    = (const float*)d_in[2];
    const float* b1    = (const float*)d_in[3];
    const float* W2    = (const float*)d_in[4];
    const float* b2    = (const float*)d_in[5];
    float* out = (float*)d_out;

    const int embN = in_sizes[0];      // N_NODES * 128
    const int M    = embN / 128;       // N_NODES
    const int E    = in_sizes[1] / 2;

    _Float16* uv = (_Float16*)d_ws;    // [M][128] fp16 = 25.6 MB
    u16* wf = (u16*)(uv + (long)M * 128);  // 32 KB fragment-ordered B'

    cvt_w_kernel<<<64, 256, 0, stream>>>(W1, wf);
    uv_gemm_kernel<<<(M + 127) / 128, 256, 0, stream>>>(emb_f, wf, uv, M);

    int nT = (E + 15) / 16;
    edge_score_kernel<<<2048, 256, 0, stream>>>(uv, idx, b1, W2, b2, out, E, nT);
}